// Round 4
// baseline (460.055 us; speedup 1.0000x reference)
//
#include <hip/hip_runtime.h>
#include <stdint.h>

#define Bc   2
#define Lc   1024
#define Pc   1024
#define Tc   2048
#define HIDc 2048
#define NHc  32
#define NKVc 8
#define Dc   64

typedef __bf16 bf16x8 __attribute__((ext_vector_type(8)));
typedef float f32x4 __attribute__((ext_vector_type(4)));

__device__ inline unsigned short f2bf(float f) {
  union { float f; uint32_t u; } v; v.f = f;
  uint32_t u = v.u;
  uint32_t r = (u + 0x7fffu + ((u >> 16) & 1u)) >> 16;
  return (unsigned short)r;
}
// cheap round-half-up bf16 (values >= 0 only)
__device__ inline unsigned short f2bf_rhu(float f) {
  union { float f; uint32_t u; } v; v.f = f;
  return (unsigned short)((v.u + 0x8000u) >> 16);
}
__device__ inline float bf2f(unsigned short h) {
  union { uint32_t u; float f; } v; v.u = ((uint32_t)h) << 16;
  return v.f;
}
__device__ inline float exp2_fast(float x) {
#if defined(__has_builtin)
#if __has_builtin(__builtin_amdgcn_exp2f)
  return __builtin_amdgcn_exp2f(x);
#else
  return exp2f(x);
#endif
#else
  return exp2f(x);
#endif
}

typedef const __attribute__((address_space(1))) unsigned int* gas1_t;
typedef __attribute__((address_space(3))) unsigned int* las3_t;
__device__ inline void gload_lds16(const void* g, void* l) {
  __builtin_amdgcn_global_load_lds((gas1_t)g, (las3_t)l, 16, 0, 0);
}

// ---------------- cast x (fp32 -> bf16) ----------------
__global__ void cast_x_kernel(const float* __restrict__ x, unsigned short* __restrict__ xb) {
  int i = (blockIdx.x * 256 + threadIdx.x) * 4;
  float4 v = *(const float4*)(x + i);
  ushort4 o;
  o.x = f2bf(v.x); o.y = f2bf(v.y); o.z = f2bf(v.z); o.w = f2bf(v.w);
  *(ushort4*)(xb + i) = o;
}

// ---- fused transpose+cast of all 4 weights ----
__global__ void transpose_all_kernel(const float* __restrict__ Wq, const float* __restrict__ Wk,
                                     const float* __restrict__ Wv, const float* __restrict__ Wo,
                                     unsigned short* __restrict__ WqkvT,
                                     unsigned short* __restrict__ WoT) {
  __shared__ float s[32][33];
  int bx = blockIdx.x, k0 = blockIdx.y * 32;
  const float* W;
  unsigned short* dst;
  int N, n0, drow;
  if (bx < 64)       { W = Wq; dst = WqkvT; N = 2048; n0 = bx * 32;        drow = n0; }
  else if (bx < 80)  { W = Wk; dst = WqkvT; N = 512;  n0 = (bx - 64) * 32; drow = 2048 + n0; }
  else if (bx < 96)  { W = Wv; dst = WqkvT; N = 512;  n0 = (bx - 80) * 32; drow = 2560 + n0; }
  else               { W = Wo; dst = WoT;   N = 2048; n0 = (bx - 96) * 32; drow = n0; }
  int tx = threadIdx.x, ty = threadIdx.y;  // (32,8)
#pragma unroll
  for (int j = 0; j < 4; ++j)
    s[ty + j * 8][tx] = W[(size_t)(k0 + ty + j * 8) * N + n0 + tx];
  __syncthreads();
#pragma unroll
  for (int j = 0; j < 4; ++j)
    dst[(size_t)(drow + ty + j * 8) * 2048 + k0 + tx] = f2bf(s[tx][ty + j * 8]);
}

// ---------------- GEMM: AITER-style pipelined K-loop ----------------
// LDS double-buffer; prefetch tile k+1 via global_load_lds, then s_waitcnt vmcnt(4)
// (waits only the 4 older loads = tile k) + RAW s_barrier -> prefetch stays in
// flight across the barrier. Second raw barrier after compute protects buffer reuse.
template <bool OUT_F32>
__global__ __launch_bounds__(256, 2) void gemm_kernel(
    const unsigned short* __restrict__ A, const unsigned short* __restrict__ BT,
    const float* __restrict__ bq, const float* __restrict__ bk, const float* __restrict__ bv,
    void* __restrict__ Cout, int N) {
  const int K = 2048;
  __shared__ unsigned short sA[2][128 * 32];
  __shared__ unsigned short sB[2][128 * 32];
  const int m0 = blockIdx.y * 128, n0 = blockIdx.x * 128;
  const int tid = threadIdx.x;
  const int lane = tid & 63, w = tid >> 6;
  const int l15 = lane & 15, quad = lane >> 4;
  const int wm = (w & 1) * 64, wn = (w >> 1) * 64;

  f32x4 acc[4][4];
#pragma unroll
  for (int i = 0; i < 4; ++i)
#pragma unroll
    for (int j = 0; j < 4; ++j) {
      f32x4 z = {0.f, 0.f, 0.f, 0.f};
      acc[i][j] = z;
    }

  const unsigned short* ga = A + (size_t)(m0 + (tid >> 2)) * K + (tid & 3) * 8;
  const unsigned short* gb = BT + (size_t)(n0 + (tid >> 2)) * K + (tid & 3) * 8;

  auto issue = [&](int tile, int buf) {
    int kb = tile * 32;
    gload_lds16(ga + kb, &sA[buf][tid * 8]);
    gload_lds16(ga + (size_t)64 * K + kb, &sA[buf][64 * 32 + tid * 8]);
    gload_lds16(gb + kb, &sB[buf][tid * 8]);
    gload_lds16(gb + (size_t)64 * K + kb, &sB[buf][64 * 32 + tid * 8]);
  };

  issue(0, 0);
  for (int t = 0; t < 64; ++t) {
    int tn = (t + 1 < 64) ? t + 1 : 63;     // clamped dummy prefetch on last iter
    issue(tn, (t + 1) & 1);
    asm volatile("s_waitcnt vmcnt(4)" ::: "memory");  // tile t's 4 loads done; prefetch in flight
    __builtin_amdgcn_s_barrier();
    const unsigned short* bA = sA[t & 1];
    const unsigned short* bB = sB[t & 1];
    bf16x8 af[4], bfr[4];
#pragma unroll
    for (int i = 0; i < 4; ++i)
      af[i] = *(const bf16x8*)(bA + (wm + i * 16 + l15) * 32 + quad * 8);
#pragma unroll
    for (int i = 0; i < 4; ++i)
      bfr[i] = *(const bf16x8*)(bB + (wn + i * 16 + l15) * 32 + quad * 8);
#pragma unroll
    for (int mi = 0; mi < 4; ++mi)
#pragma unroll
      for (int ni = 0; ni < 4; ++ni)
        acc[mi][ni] = __builtin_amdgcn_mfma_f32_16x16x32_bf16(af[mi], bfr[ni], acc[mi][ni], 0, 0, 0);
    asm volatile("s_waitcnt lgkmcnt(0)" ::: "memory");  // ds_reads retired
    __builtin_amdgcn_s_barrier();                       // safe to overwrite buf next iter
  }

#pragma unroll
  for (int mi = 0; mi < 4; ++mi)
#pragma unroll
    for (int ni = 0; ni < 4; ++ni) {
      int col = n0 + wn + ni * 16 + l15;
      float bvv = 0.f;
      if (bq) bvv = (col < 2048) ? bq[col] : (col < 2560 ? bk[col - 2048] : bv[col - 2560]);
#pragma unroll
      for (int r = 0; r < 4; ++r) {
        int row = m0 + wm + mi * 16 + quad * 4 + r;
        float v = acc[mi][ni][r] + bvv;
        if (OUT_F32)
          ((float*)Cout)[(size_t)row * N + col] = v;
        else
          ((unsigned short*)Cout)[(size_t)row * N + col] = f2bf(v);
      }
    }
}

// ------- fused KV-cache build -------
__global__ void build_kv_kernel(const unsigned short* __restrict__ qkv,
                                const float* __restrict__ past_k,
                                const float* __restrict__ past_v,
                                const float* __restrict__ cosb, const float* __restrict__ sinb,
                                unsigned short* __restrict__ Kc,
                                unsigned short* __restrict__ Vc) {
  __shared__ unsigned short s[32][72];
  int tid = threadIdx.x;
  if (blockIdx.x < 4096) {
    int idx = blockIdx.x * 256 + tid;
    int d = idx & 31;
    int t = (idx >> 5) & 2047;
    int bh = idx >> 16;
    size_t obase = ((size_t)bh * 2048 + t) * 64 + d;
    if (t < 1024) {
      size_t pb = ((size_t)bh * 1024 + t) * 64 + d;
      Kc[obase] = f2bf(past_k[pb]);
      Kc[obase + 32] = f2bf(past_k[pb + 32]);
    } else {
      int l = t - 1024;
      int b = bh >> 3, hk = bh & 7;
      size_t qb = ((size_t)(b * 1024 + l)) * 3072 + 2048 + hk * 64 + d;
      float k0 = bf2f(qkv[qb]), k1 = bf2f(qkv[qb + 32]);
      float c = cosb[l * 64 + d], sn = sinb[l * 64 + d];
      Kc[obase] = f2bf(k0 * c - k1 * sn);
      Kc[obase + 32] = f2bf(k1 * c + k0 * sn);
    }
  } else {
    int bx = blockIdx.x - 4096;
    int t0 = (bx & 63) * 32;
    int bh = bx >> 6;
#pragma unroll
    for (int i = 0; i < 8; ++i) {
      int e = tid + 256 * i;
      int tl = e >> 6, d = e & 63;
      int t = t0 + tl;
      unsigned short val;
      if (t < 1024) {
        val = f2bf(past_v[((size_t)bh * 1024 + t) * 64 + d]);
      } else {
        int b = bh >> 3, hk = bh & 7;
        int l = t - 1024;
        val = qkv[(size_t)(b * 1024 + l) * 3072 + 2560 + hk * 64 + d];
      }
      s[tl][d] = val;
    }
    __syncthreads();
#pragma unroll
    for (int i = 0; i < 8; ++i) {
      int e = tid + 256 * i;
      int d = e >> 5, tl = e & 31;
      Vc[((size_t)bh * 64 + d) * 2048 + t0 + tl] = s[tl][d];
    }
  }
}

// ---------------- flash attention v4: in-block T-split (4 waves) ----------------
// Block = 4 waves, all on the same 32 q-rows; wave w processes key-tiles
// kt = w, w+4, w+8, ... (barrier-free main loop, round-2 simple loads).
// Softmax-lite (exp2, no running max) => partials are additive across splits:
// block-level combine via LDS atomicAdd into the dead sP region, then one
// normalized bf16 store. 4x the waves of v2/v3 for latency hiding.
#define LSTR 72
__global__ __launch_bounds__(256, 4) void attn_kernel(
    const unsigned short* __restrict__ qkv,  // [B*L][3072]
    const unsigned short* __restrict__ Kc,   // [B][NKV][T][D]
    const unsigned short* __restrict__ Vc,   // [B][NKV][D][T]
    const float* __restrict__ cosb, const float* __restrict__ sinb,
    unsigned short* __restrict__ O) {        // [B*L][2048]
  __shared__ __align__(16) char smem[4 * 32 * LSTR * 2];  // sP[4 waves] / reduce overlay

  int flat = blockIdx.x;           // 0..2047
  int p = flat & 7, s = flat >> 3;
  int pair = p * 2 + (s & 1);      // b*8+hk  (XCD-swizzled)
  int b = pair >> 3, hk = pair & 7;
  int inner = s >> 1;
  int hi = inner & 3, qt = inner >> 2;
  int h = hk * 4 + hi;
  int q0 = qt * 32;

  const int tid = threadIdx.x;
  const int lane = tid & 63, w = tid >> 6;
  const int l15 = lane & 15, quad = lane >> 4;

  unsigned short* sP = (unsigned short*)smem + w * (32 * LSTR);

  union U8 { bf16x8 v; unsigned short u[8]; };

  // ---- Q fragments: inline RoPE + fold in scale*log2(e) (same for all 4 waves) ----
  const float SC = 0.125f * 1.44269504f;
  bf16x8 qf[2][2];
#pragma unroll
  for (int mi = 0; mi < 2; ++mi) {
    int row = q0 + mi * 16 + l15;
    const unsigned short* qrow = qkv + (size_t)(b * 1024 + row) * 3072 + h * 64;
    int d0 = quad * 8;
    U8 lo, hig, f0, f1;
    lo.v = *(const bf16x8*)(qrow + d0);
    hig.v = *(const bf16x8*)(qrow + 32 + d0);
    float4 ca = *(const float4*)(cosb + row * 64 + d0);
    float4 cb = *(const float4*)(cosb + row * 64 + d0 + 4);
    float4 sa = *(const float4*)(sinb + row * 64 + d0);
    float4 sb = *(const float4*)(sinb + row * 64 + d0 + 4);
    float c[8] = {ca.x, ca.y, ca.z, ca.w, cb.x, cb.y, cb.z, cb.w};
    float sn[8] = {sa.x, sa.y, sa.z, sa.w, sb.x, sb.y, sb.z, sb.w};
#pragma unroll
    for (int j = 0; j < 8; ++j) {
      float ql = bf2f(lo.u[j]), qh = bf2f(hig.u[j]);
      float cc = c[j] * SC, ss = sn[j] * SC;
      f0.u[j] = f2bf(ql * cc - qh * ss);
      f1.u[j] = f2bf(qh * cc + ql * ss);
    }
    qf[mi][0] = f0.v;
    qf[mi][1] = f1.v;
  }

  const unsigned short* Kb = Kc + ((size_t)b * 8 + hk) * (2048 * 64);
  const unsigned short* Vb = Vc + ((size_t)b * 8 + hk) * (64 * 2048);

  f32x4 oacc[2][4];
  float lsum[2][4];
#pragma unroll
  for (int mi = 0; mi < 2; ++mi) {
#pragma unroll
    for (int nd = 0; nd < 4; ++nd) {
      f32x4 z = {0.f, 0.f, 0.f, 0.f};
      oacc[mi][nd] = z;
    }
#pragma unroll
    for (int r = 0; r < 4; ++r) lsum[mi][r] = 0.f;
  }

  const int ntile = (q0 + 32 + 1024 + 63) >> 6;  // 17..32
  for (int kt = w; kt < ntile; kt += 4) {
    const int t0 = kt * 64;
    bf16x8 kf[2][4];
#pragma unroll
    for (int ks = 0; ks < 2; ++ks)
#pragma unroll
      for (int nt = 0; nt < 4; ++nt)
        kf[ks][nt] = *(const bf16x8*)(Kb + (size_t)(t0 + nt * 16 + l15) * 64 + ks * 32 + quad * 8);
    bf16x8 vf[2][4];
#pragma unroll
    for (int tk = 0; tk < 2; ++tk)
#pragma unroll
      for (int nd = 0; nd < 4; ++nd)
        vf[tk][nd] = *(const bf16x8*)(Vb + (size_t)(nd * 16 + l15) * 2048 + t0 + tk * 32 + quad * 8);

    f32x4 sacc[2][4];
#pragma unroll
    for (int mi = 0; mi < 2; ++mi)
#pragma unroll
      for (int nt = 0; nt < 4; ++nt) {
        f32x4 z = {0.f, 0.f, 0.f, 0.f};
        sacc[mi][nt] = z;
      }
#pragma unroll
    for (int mi = 0; mi < 2; ++mi)
#pragma unroll
      for (int ks = 0; ks < 2; ++ks)
#pragma unroll
        for (int nt = 0; nt < 4; ++nt)
          sacc[mi][nt] = __builtin_amdgcn_mfma_f32_16x16x32_bf16(qf[mi][ks], kf[ks][nt], sacc[mi][nt], 0, 0, 0);

    const bool diag = (t0 + 63 > q0 + Pc);
    if (!diag) {
#pragma unroll
      for (int mi = 0; mi < 2; ++mi)
#pragma unroll
        for (int nt = 0; nt < 4; ++nt)
#pragma unroll
          for (int r = 0; r < 4; ++r) {
            float pv = exp2_fast(sacc[mi][nt][r]);
            lsum[mi][r] += pv;
            sP[(mi * 16 + quad * 4 + r) * LSTR + nt * 16 + l15] = f2bf_rhu(pv);
          }
    } else {
#pragma unroll
      for (int mi = 0; mi < 2; ++mi)
#pragma unroll
        for (int nt = 0; nt < 4; ++nt)
#pragma unroll
          for (int r = 0; r < 4; ++r) {
            int tg = t0 + nt * 16 + l15;
            int rg = q0 + mi * 16 + quad * 4 + r;
            float pv = (tg > rg + Pc) ? 0.f : exp2_fast(sacc[mi][nt][r]);
            lsum[mi][r] += pv;
            sP[(mi * 16 + quad * 4 + r) * LSTR + nt * 16 + l15] = f2bf_rhu(pv);
          }
    }
    asm volatile("s_waitcnt lgkmcnt(0)" ::: "memory");

#pragma unroll
    for (int mi = 0; mi < 2; ++mi)
#pragma unroll
      for (int tk = 0; tk < 2; ++tk) {
        bf16x8 a = *(const bf16x8*)(sP + (mi * 16 + l15) * LSTR + tk * 32 + quad * 8);
#pragma unroll
        for (int nd = 0; nd < 4; ++nd)
          oacc[mi][nd] = __builtin_amdgcn_mfma_f32_16x16x32_bf16(a, vf[tk][nd], oacc[mi][nd], 0, 0, 0);
      }
  }

  // ---- block-level combine of additive partials (overlay on dead sP) ----
  __syncthreads();
  float* sAcc = (float*)smem;                      // [32][68]
  float* sLl  = (float*)smem + 32 * 68;            // [32]
  for (int i = tid; i < 32 * 68 + 32; i += 256) ((float*)smem)[i] = 0.f;
  __syncthreads();

#pragma unroll
  for (int mi = 0; mi < 2; ++mi)
#pragma unroll
    for (int r = 0; r < 4; ++r) {
      float v = lsum[mi][r];
      v += __shfl_xor(v, 1);
      v += __shfl_xor(v, 2);
      v += __shfl_xor(v, 4);
      v += __shfl_xor(v, 8);
      if (l15 == 0) atomicAdd(&sLl[mi * 16 + quad * 4 + r], v);
    }
#pragma unroll
  for (int mi = 0; mi < 2; ++mi)
#pragma unroll
    for (int nd = 0; nd < 4; ++nd)
#pragma unroll
      for (int r = 0; r < 4; ++r)
        atomicAdd(&sAcc[(mi * 16 + quad * 4 + r) * 68 + nd * 16 + l15], oacc[mi][nd][r]);
  __syncthreads();

  // normalize + vectorized store: thread -> (row=tid>>3, cols (tid&7)*8..+7)
  {
    int r32 = tid >> 3, c = (tid & 7) * 8;
    float inv = 1.f / sLl[r32];
    union { ushort4 u4[2]; unsigned short u[8]; uint4 q; } o;
#pragma unroll
    for (int j = 0; j < 8; ++j) o.u[j] = f2bf(sAcc[r32 * 68 + c + j] * inv);
    int row = b * 1024 + q0 + r32;
    int col = h * 64 + c;
    *(uint4*)(O + (size_t)row * 2048 + col) = o.q;
  }
}

extern "C" void kernel_launch(void* const* d_in, const int* in_sizes, int n_in,
                              void* d_out, int out_size, void* d_ws, size_t ws_size,
                              hipStream_t stream) {
  const float* x      = (const float*)d_in[0];
  const float* cosb   = (const float*)d_in[2];
  const float* sinb   = (const float*)d_in[3];
  const float* past_k = (const float*)d_in[4];
  const float* past_v = (const float*)d_in[5];
  const float* Wq     = (const float*)d_in[6];
  const float* bq     = (const float*)d_in[7];
  const float* Wk     = (const float*)d_in[8];
  const float* bk     = (const float*)d_in[9];
  const float* Wv     = (const float*)d_in[10];
  const float* bv     = (const float*)d_in[11];
  const float* Wo     = (const float*)d_in[12];
  float* out = (float*)d_out;

  char* ws = (char*)d_ws;
  unsigned short* xb    = (unsigned short*)(ws + ((size_t)0 << 20));   // 8 MB
  unsigned short* WqkvT = (unsigned short*)(ws + ((size_t)8 << 20));   // 12 MB
  unsigned short* WoT   = (unsigned short*)(ws + ((size_t)20 << 20));  // 8 MB
  unsigned short* qkvb  = (unsigned short*)(ws + ((size_t)28 << 20));  // 12 MB
  unsigned short* Kc    = (unsigned short*)(ws + ((size_t)40 << 20));  // 4 MB
  unsigned short* Vc    = (unsigned short*)(ws + ((size_t)44 << 20));  // 4 MB
  unsigned short* attno = (unsigned short*)(ws + ((size_t)48 << 20));  // 8 MB

  cast_x_kernel<<<4096, 256, 0, stream>>>(x, xb);
  transpose_all_kernel<<<dim3(160, 64), dim3(32, 8), 0, stream>>>(Wq, Wk, Wv, Wo, WqkvT, WoT);

  gemm_kernel<false><<<dim3(24, 16), 256, 0, stream>>>(xb, WqkvT, bq, bk, bv, qkvb, 3072);

  build_kv_kernel<<<5120, 256, 0, stream>>>(qkvb, past_k, past_v, cosb, sinb, Kc, Vc);

  attn_kernel<<<2048, 256, 0, stream>>>(qkvb, Kc, Vc, cosb, sinb, attno);

  gemm_kernel<true><<<dim3(16, 16), 256, 0, stream>>>(attno, WoT, nullptr, nullptr, nullptr, out, 2048);
}

// Round 5
// 395.041 us; speedup vs baseline: 1.1646x; 1.1646x over previous
//
#include <hip/hip_runtime.h>
#include <stdint.h>

#define Bc   2
#define Lc   1024
#define Pc   1024
#define Tc   2048
#define HIDc 2048
#define NHc  32
#define NKVc 8
#define Dc   64

typedef __bf16 bf16x8 __attribute__((ext_vector_type(8)));
typedef float f32x4 __attribute__((ext_vector_type(4)));

__device__ inline unsigned short f2bf(float f) {
  union { float f; uint32_t u; } v; v.f = f;
  uint32_t u = v.u;
  uint32_t r = (u + 0x7fffu + ((u >> 16) & 1u)) >> 16;
  return (unsigned short)r;
}
// cheap round-half-up bf16 (values >= 0 only)
__device__ inline unsigned short f2bf_rhu(float f) {
  union { float f; uint32_t u; } v; v.f = f;
  return (unsigned short)((v.u + 0x8000u) >> 16);
}
__device__ inline float bf2f(unsigned short h) {
  union { uint32_t u; float f; } v; v.u = ((uint32_t)h) << 16;
  return v.f;
}
__device__ inline float exp2_fast(float x) {
#if defined(__has_builtin)
#if __has_builtin(__builtin_amdgcn_exp2f)
  return __builtin_amdgcn_exp2f(x);
#else
  return exp2f(x);
#endif
#else
  return exp2f(x);
#endif
}

typedef const __attribute__((address_space(1))) unsigned int* gas1_t;
typedef __attribute__((address_space(3))) unsigned int* las3_t;
__device__ inline void gload_lds16(const void* g, void* l) {
  __builtin_amdgcn_global_load_lds((gas1_t)g, (las3_t)l, 16, 0, 0);
}

// ---------------- cast x (fp32 -> bf16) ----------------
__global__ void cast_x_kernel(const float* __restrict__ x, unsigned short* __restrict__ xb) {
  int i = (blockIdx.x * 256 + threadIdx.x) * 4;
  float4 v = *(const float4*)(x + i);
  ushort4 o;
  o.x = f2bf(v.x); o.y = f2bf(v.y); o.z = f2bf(v.z); o.w = f2bf(v.w);
  *(ushort4*)(xb + i) = o;
}

// ---- fused transpose+cast of all 4 weights ----
__global__ void transpose_all_kernel(const float* __restrict__ Wq, const float* __restrict__ Wk,
                                     const float* __restrict__ Wv, const float* __restrict__ Wo,
                                     unsigned short* __restrict__ WqkvT,
                                     unsigned short* __restrict__ WoT) {
  __shared__ float s[32][33];
  int bx = blockIdx.x, k0 = blockIdx.y * 32;
  const float* W;
  unsigned short* dst;
  int N, n0, drow;
  if (bx < 64)       { W = Wq; dst = WqkvT; N = 2048; n0 = bx * 32;        drow = n0; }
  else if (bx < 80)  { W = Wk; dst = WqkvT; N = 512;  n0 = (bx - 64) * 32; drow = 2048 + n0; }
  else if (bx < 96)  { W = Wv; dst = WqkvT; N = 512;  n0 = (bx - 80) * 32; drow = 2560 + n0; }
  else               { W = Wo; dst = WoT;   N = 2048; n0 = (bx - 96) * 32; drow = n0; }
  int tx = threadIdx.x, ty = threadIdx.y;  // (32,8)
#pragma unroll
  for (int j = 0; j < 4; ++j)
    s[ty + j * 8][tx] = W[(size_t)(k0 + ty + j * 8) * N + n0 + tx];
  __syncthreads();
#pragma unroll
  for (int j = 0; j < 4; ++j)
    dst[(size_t)(drow + ty + j * 8) * 2048 + k0 + tx] = f2bf(s[tx][ty + j * 8]);
}

// ---------------- GEMM: TM x 128 tile, AITER-style pipelined K-loop ----------------
// TM=64 gives 2x the blocks (3/CU at these shapes, balanced CU waves) at the cost
// of 2x staging per MFMA. LDS dbuf + global_load_lds prefetch of tile k+1 +
// s_waitcnt vmcnt(L) (never 0) -> prefetch stays in flight across the barrier.
template <int TM, bool OUT_F32>
__global__ __launch_bounds__(256, 2) void gemm_kernel(
    const unsigned short* __restrict__ A, const unsigned short* __restrict__ BT,
    const float* __restrict__ bq, const float* __restrict__ bk, const float* __restrict__ bv,
    void* __restrict__ Cout, int N) {
  const int K = 2048;
  const int MI = TM / 32;       // m-frags per wave
  __shared__ unsigned short sA[2][TM * 32];
  __shared__ unsigned short sB[2][128 * 32];
  const int m0 = blockIdx.y * TM, n0 = blockIdx.x * 128;
  const int tid = threadIdx.x;
  const int lane = tid & 63, w = tid >> 6;
  const int l15 = lane & 15, quad = lane >> 4;
  const int wm = (w & 1) * (TM / 2), wn = (w >> 1) * 64;

  f32x4 acc[MI][4];
#pragma unroll
  for (int i = 0; i < MI; ++i)
#pragma unroll
    for (int j = 0; j < 4; ++j) {
      f32x4 z = {0.f, 0.f, 0.f, 0.f};
      acc[i][j] = z;
    }

  const unsigned short* ga = A + (size_t)(m0 + (tid >> 2)) * K + (tid & 3) * 8;
  const unsigned short* gb = BT + (size_t)(n0 + (tid >> 2)) * K + (tid & 3) * 8;

  auto issue = [&](int tile, int buf) {
    int kb = tile * 32;
#pragma unroll
    for (int i = 0; i < TM / 64; ++i)
      gload_lds16(ga + (size_t)(i * 64) * K + kb, &sA[buf][i * 64 * 32 + tid * 8]);
    gload_lds16(gb + kb, &sB[buf][tid * 8]);
    gload_lds16(gb + (size_t)64 * K + kb, &sB[buf][64 * 32 + tid * 8]);
  };

  issue(0, 0);
  for (int t = 0; t < 64; ++t) {
    int tn = (t + 1 < 64) ? t + 1 : 63;  // clamped dummy prefetch on last iter
    issue(tn, (t + 1) & 1);
    if (TM == 128)
      asm volatile("s_waitcnt vmcnt(4)" ::: "memory");
    else
      asm volatile("s_waitcnt vmcnt(3)" ::: "memory");
    __builtin_amdgcn_s_barrier();
    const unsigned short* bA = sA[t & 1];
    const unsigned short* bB = sB[t & 1];
    bf16x8 af[MI], bfr[4];
#pragma unroll
    for (int i = 0; i < MI; ++i)
      af[i] = *(const bf16x8*)(bA + (wm + i * 16 + l15) * 32 + quad * 8);
#pragma unroll
    for (int i = 0; i < 4; ++i)
      bfr[i] = *(const bf16x8*)(bB + (wn + i * 16 + l15) * 32 + quad * 8);
#pragma unroll
    for (int mi = 0; mi < MI; ++mi)
#pragma unroll
      for (int ni = 0; ni < 4; ++ni)
        acc[mi][ni] = __builtin_amdgcn_mfma_f32_16x16x32_bf16(af[mi], bfr[ni], acc[mi][ni], 0, 0, 0);
    asm volatile("s_waitcnt lgkmcnt(0)" ::: "memory");
    __builtin_amdgcn_s_barrier();
  }

#pragma unroll
  for (int mi = 0; mi < MI; ++mi)
#pragma unroll
    for (int ni = 0; ni < 4; ++ni) {
      int col = n0 + wn + ni * 16 + l15;
      float bvv = 0.f;
      if (bq) bvv = (col < 2048) ? bq[col] : (col < 2560 ? bk[col - 2048] : bv[col - 2560]);
#pragma unroll
      for (int r = 0; r < 4; ++r) {
        int row = m0 + wm + mi * 16 + quad * 4 + r;
        float v = acc[mi][ni][r] + bvv;
        if (OUT_F32)
          ((float*)Cout)[(size_t)row * N + col] = v;
        else
          ((unsigned short*)Cout)[(size_t)row * N + col] = f2bf(v);
      }
    }
}

// ------- fused KV-cache build -------
__global__ void build_kv_kernel(const unsigned short* __restrict__ qkv,
                                const float* __restrict__ past_k,
                                const float* __restrict__ past_v,
                                const float* __restrict__ cosb, const float* __restrict__ sinb,
                                unsigned short* __restrict__ Kc,
                                unsigned short* __restrict__ Vc) {
  __shared__ unsigned short s[32][72];
  int tid = threadIdx.x;
  if (blockIdx.x < 4096) {
    int idx = blockIdx.x * 256 + tid;
    int d = idx & 31;
    int t = (idx >> 5) & 2047;
    int bh = idx >> 16;
    size_t obase = ((size_t)bh * 2048 + t) * 64 + d;
    if (t < 1024) {
      size_t pb = ((size_t)bh * 1024 + t) * 64 + d;
      Kc[obase] = f2bf(past_k[pb]);
      Kc[obase + 32] = f2bf(past_k[pb + 32]);
    } else {
      int l = t - 1024;
      int b = bh >> 3, hk = bh & 7;
      size_t qb = ((size_t)(b * 1024 + l)) * 3072 + 2048 + hk * 64 + d;
      float k0 = bf2f(qkv[qb]), k1 = bf2f(qkv[qb + 32]);
      float c = cosb[l * 64 + d], sn = sinb[l * 64 + d];
      Kc[obase] = f2bf(k0 * c - k1 * sn);
      Kc[obase + 32] = f2bf(k1 * c + k0 * sn);
    }
  } else {
    int bx = blockIdx.x - 4096;
    int t0 = (bx & 63) * 32;
    int bh = bx >> 6;
#pragma unroll
    for (int i = 0; i < 8; ++i) {
      int e = tid + 256 * i;
      int tl = e >> 6, d = e & 63;
      int t = t0 + tl;
      unsigned short val;
      if (t < 1024) {
        val = f2bf(past_v[((size_t)bh * 1024 + t) * 64 + d]);
      } else {
        int b = bh >> 3, hk = bh & 7;
        int l = t - 1024;
        val = qkv[(size_t)(b * 1024 + l) * 3072 + 2560 + hk * 64 + d];
      }
      s[tl][d] = val;
    }
    __syncthreads();
#pragma unroll
    for (int i = 0; i < 8; ++i) {
      int e = tid + 256 * i;
      int d = e >> 5, tl = e & 31;
      Vc[((size_t)bh * 64 + d) * 2048 + t0 + tl] = s[tl][d];
    }
  }
}

// ---------------- flash attention v5: T-split, spill-free ----------------
// v4 structure (4 waves share 32 q-rows, wave w takes key-tiles kt%4==w, additive
// partials combined in LDS) but: launch_bounds (256,2) so the allocator has 256
// VGPRs (v4's (256,4) forced 64 -> 280MB scratch spill), and V-fragment loads
// issued AFTER the QK MFMAs (shorter vf lifetime; exp2 hides V latency).
#define LSTR 72
__global__ __launch_bounds__(256, 2) void attn_kernel(
    const unsigned short* __restrict__ qkv,  // [B*L][3072]
    const unsigned short* __restrict__ Kc,   // [B][NKV][T][D]
    const unsigned short* __restrict__ Vc,   // [B][NKV][D][T]
    const float* __restrict__ cosb, const float* __restrict__ sinb,
    unsigned short* __restrict__ O) {        // [B*L][2048]
  __shared__ __align__(16) char smem[4 * 32 * LSTR * 2];  // sP[4 waves] / reduce overlay

  int flat = blockIdx.x;           // 0..2047
  int p = flat & 7, s = flat >> 3;
  int pair = p * 2 + (s & 1);      // b*8+hk  (XCD-swizzled)
  int b = pair >> 3, hk = pair & 7;
  int inner = s >> 1;
  int hi = inner & 3, qt = inner >> 2;
  int h = hk * 4 + hi;
  int q0 = qt * 32;

  const int tid = threadIdx.x;
  const int lane = tid & 63, w = tid >> 6;
  const int l15 = lane & 15, quad = lane >> 4;

  unsigned short* sP = (unsigned short*)smem + w * (32 * LSTR);

  union U8 { bf16x8 v; unsigned short u[8]; };

  // ---- Q fragments: inline RoPE + fold in scale*log2(e) ----
  const float SC = 0.125f * 1.44269504f;
  bf16x8 qf[2][2];
#pragma unroll
  for (int mi = 0; mi < 2; ++mi) {
    int row = q0 + mi * 16 + l15;
    const unsigned short* qrow = qkv + (size_t)(b * 1024 + row) * 3072 + h * 64;
    int d0 = quad * 8;
    U8 lo, hig, f0, f1;
    lo.v = *(const bf16x8*)(qrow + d0);
    hig.v = *(const bf16x8*)(qrow + 32 + d0);
    float4 ca = *(const float4*)(cosb + row * 64 + d0);
    float4 cb = *(const float4*)(cosb + row * 64 + d0 + 4);
    float4 sa = *(const float4*)(sinb + row * 64 + d0);
    float4 sb = *(const float4*)(sinb + row * 64 + d0 + 4);
    float c[8] = {ca.x, ca.y, ca.z, ca.w, cb.x, cb.y, cb.z, cb.w};
    float sn[8] = {sa.x, sa.y, sa.z, sa.w, sb.x, sb.y, sb.z, sb.w};
#pragma unroll
    for (int j = 0; j < 8; ++j) {
      float ql = bf2f(lo.u[j]), qh = bf2f(hig.u[j]);
      float cc = c[j] * SC, ss = sn[j] * SC;
      f0.u[j] = f2bf(ql * cc - qh * ss);
      f1.u[j] = f2bf(qh * cc + ql * ss);
    }
    qf[mi][0] = f0.v;
    qf[mi][1] = f1.v;
  }

  const unsigned short* Kb = Kc + ((size_t)b * 8 + hk) * (2048 * 64);
  const unsigned short* Vb = Vc + ((size_t)b * 8 + hk) * (64 * 2048);

  f32x4 oacc[2][4];
  float lsum[2][4];
#pragma unroll
  for (int mi = 0; mi < 2; ++mi) {
#pragma unroll
    for (int nd = 0; nd < 4; ++nd) {
      f32x4 z = {0.f, 0.f, 0.f, 0.f};
      oacc[mi][nd] = z;
    }
#pragma unroll
    for (int r = 0; r < 4; ++r) lsum[mi][r] = 0.f;
  }

  const int ntile = (q0 + 32 + 1024 + 63) >> 6;  // 17..32
  for (int kt = w; kt < ntile; kt += 4) {
    const int t0 = kt * 64;
    bf16x8 kf[2][4];
#pragma unroll
    for (int ks = 0; ks < 2; ++ks)
#pragma unroll
      for (int nt = 0; nt < 4; ++nt)
        kf[ks][nt] = *(const bf16x8*)(Kb + (size_t)(t0 + nt * 16 + l15) * 64 + ks * 32 + quad * 8);

    f32x4 sacc[2][4];
#pragma unroll
    for (int mi = 0; mi < 2; ++mi)
#pragma unroll
      for (int nt = 0; nt < 4; ++nt) {
        f32x4 z = {0.f, 0.f, 0.f, 0.f};
        sacc[mi][nt] = z;
      }
#pragma unroll
    for (int mi = 0; mi < 2; ++mi)
#pragma unroll
      for (int ks = 0; ks < 2; ++ks)
#pragma unroll
        for (int nt = 0; nt < 4; ++nt)
          sacc[mi][nt] = __builtin_amdgcn_mfma_f32_16x16x32_bf16(qf[mi][ks], kf[ks][nt], sacc[mi][nt], 0, 0, 0);

    // V loads issued after QK; exp2 below hides their latency.
    bf16x8 vf[2][4];
#pragma unroll
    for (int tk = 0; tk < 2; ++tk)
#pragma unroll
      for (int nd = 0; nd < 4; ++nd)
        vf[tk][nd] = *(const bf16x8*)(Vb + (size_t)(nd * 16 + l15) * 2048 + t0 + tk * 32 + quad * 8);

    const bool diag = (t0 + 63 > q0 + Pc);
    if (!diag) {
#pragma unroll
      for (int mi = 0; mi < 2; ++mi)
#pragma unroll
        for (int nt = 0; nt < 4; ++nt)
#pragma unroll
          for (int r = 0; r < 4; ++r) {
            float pv = exp2_fast(sacc[mi][nt][r]);
            lsum[mi][r] += pv;
            sP[(mi * 16 + quad * 4 + r) * LSTR + nt * 16 + l15] = f2bf_rhu(pv);
          }
    } else {
#pragma unroll
      for (int mi = 0; mi < 2; ++mi)
#pragma unroll
        for (int nt = 0; nt < 4; ++nt)
#pragma unroll
          for (int r = 0; r < 4; ++r) {
            int tg = t0 + nt * 16 + l15;
            int rg = q0 + mi * 16 + quad * 4 + r;
            float pv = (tg > rg + Pc) ? 0.f : exp2_fast(sacc[mi][nt][r]);
            lsum[mi][r] += pv;
            sP[(mi * 16 + quad * 4 + r) * LSTR + nt * 16 + l15] = f2bf_rhu(pv);
          }
    }
    asm volatile("s_waitcnt lgkmcnt(0)" ::: "memory");

#pragma unroll
    for (int mi = 0; mi < 2; ++mi)
#pragma unroll
      for (int tk = 0; tk < 2; ++tk) {
        bf16x8 a = *(const bf16x8*)(sP + (mi * 16 + l15) * LSTR + tk * 32 + quad * 8);
#pragma unroll
        for (int nd = 0; nd < 4; ++nd)
          oacc[mi][nd] = __builtin_amdgcn_mfma_f32_16x16x32_bf16(a, vf[tk][nd], oacc[mi][nd], 0, 0, 0);
      }
  }

  // ---- block-level combine of additive partials (overlay on dead sP) ----
  __syncthreads();
  float* sAcc = (float*)smem;                      // [32][68]
  float* sLl  = (float*)smem + 32 * 68;            // [32]
  for (int i = tid; i < 32 * 68 + 32; i += 256) ((float*)smem)[i] = 0.f;
  __syncthreads();

#pragma unroll
  for (int mi = 0; mi < 2; ++mi)
#pragma unroll
    for (int r = 0; r < 4; ++r) {
      float v = lsum[mi][r];
      v += __shfl_xor(v, 1);
      v += __shfl_xor(v, 2);
      v += __shfl_xor(v, 4);
      v += __shfl_xor(v, 8);
      if (l15 == 0) atomicAdd(&sLl[mi * 16 + quad * 4 + r], v);
    }
#pragma unroll
  for (int mi = 0; mi < 2; ++mi)
#pragma unroll
    for (int nd = 0; nd < 4; ++nd)
#pragma unroll
      for (int r = 0; r < 4; ++r)
        atomicAdd(&sAcc[(mi * 16 + quad * 4 + r) * 68 + nd * 16 + l15], oacc[mi][nd][r]);
  __syncthreads();

  // normalize + vectorized store
  {
    int r32 = tid >> 3, c = (tid & 7) * 8;
    float inv = 1.f / sLl[r32];
    union { unsigned short u[8]; uint4 q; } o;
#pragma unroll
    for (int j = 0; j < 8; ++j) o.u[j] = f2bf(sAcc[r32 * 68 + c + j] * inv);
    int row = b * 1024 + q0 + r32;
    int col = h * 64 + c;
    *(uint4*)(O + (size_t)row * 2048 + col) = o.q;
  }
}

extern "C" void kernel_launch(void* const* d_in, const int* in_sizes, int n_in,
                              void* d_out, int out_size, void* d_ws, size_t ws_size,
                              hipStream_t stream) {
  const float* x      = (const float*)d_in[0];
  const float* cosb   = (const float*)d_in[2];
  const float* sinb   = (const float*)d_in[3];
  const float* past_k = (const float*)d_in[4];
  const float* past_v = (const float*)d_in[5];
  const float* Wq     = (const float*)d_in[6];
  const float* bq     = (const float*)d_in[7];
  const float* Wk     = (const float*)d_in[8];
  const float* bk     = (const float*)d_in[9];
  const float* Wv     = (const float*)d_in[10];
  const float* bv     = (const float*)d_in[11];
  const float* Wo     = (const float*)d_in[12];
  float* out = (float*)d_out;

  char* ws = (char*)d_ws;
  unsigned short* xb    = (unsigned short*)(ws + ((size_t)0 << 20));   // 8 MB
  unsigned short* WqkvT = (unsigned short*)(ws + ((size_t)8 << 20));   // 12 MB
  unsigned short* WoT   = (unsigned short*)(ws + ((size_t)20 << 20));  // 8 MB
  unsigned short* qkvb  = (unsigned short*)(ws + ((size_t)28 << 20));  // 12 MB
  unsigned short* Kc    = (unsigned short*)(ws + ((size_t)40 << 20));  // 4 MB
  unsigned short* Vc    = (unsigned short*)(ws + ((size_t)44 << 20));  // 4 MB
  unsigned short* attno = (unsigned short*)(ws + ((size_t)48 << 20));  // 8 MB

  cast_x_kernel<<<4096, 256, 0, stream>>>(x, xb);
  transpose_all_kernel<<<dim3(160, 64), dim3(32, 8), 0, stream>>>(Wq, Wk, Wv, Wo, WqkvT, WoT);

  gemm_kernel<64, false><<<dim3(24, 32), 256, 0, stream>>>(xb, WqkvT, bq, bk, bv, qkvb, 3072);

  build_kv_kernel<<<5120, 256, 0, stream>>>(qkvb, past_k, past_v, cosb, sinb, Kc, Vc);

  attn_kernel<<<2048, 256, 0, stream>>>(qkvb, Kc, Vc, cosb, sinb, attno);

  gemm_kernel<64, true><<<dim3(16, 32), 256, 0, stream>>>(attno, WoT, nullptr, nullptr, nullptr, out, 2048);
}

// Round 6
// 272.529 us; speedup vs baseline: 1.6881x; 1.4495x over previous
//
#include <hip/hip_runtime.h>
#include <stdint.h>

#define Bc   2
#define Lc   1024
#define Pc   1024
#define Tc   2048
#define HIDc 2048
#define NHc  32
#define NKVc 8
#define Dc   64

typedef __bf16 bf16x8 __attribute__((ext_vector_type(8)));
typedef float f32x4 __attribute__((ext_vector_type(4)));

__device__ inline unsigned short f2bf(float f) {
  union { float f; uint32_t u; } v; v.f = f;
  uint32_t u = v.u;
  uint32_t r = (u + 0x7fffu + ((u >> 16) & 1u)) >> 16;
  return (unsigned short)r;
}
// cheap round-half-up bf16 (values >= 0 only)
__device__ inline unsigned short f2bf_rhu(float f) {
  union { float f; uint32_t u; } v; v.f = f;
  return (unsigned short)((v.u + 0x8000u) >> 16);
}
__device__ inline float bf2f(unsigned short h) {
  union { uint32_t u; float f; } v; v.u = ((uint32_t)h) << 16;
  return v.f;
}
__device__ inline float exp2_fast(float x) {
#if defined(__has_builtin)
#if __has_builtin(__builtin_amdgcn_exp2f)
  return __builtin_amdgcn_exp2f(x);
#else
  return exp2f(x);
#endif
#else
  return exp2f(x);
#endif
}

typedef const __attribute__((address_space(1))) unsigned int* gas1_t;
typedef __attribute__((address_space(3))) unsigned int* las3_t;
__device__ inline void gload_lds16(const void* g, void* l) {
  __builtin_amdgcn_global_load_lds((gas1_t)g, (las3_t)l, 16, 0, 0);
}

// ---------------- cast x (fp32 -> bf16) ----------------
__global__ void cast_x_kernel(const float* __restrict__ x, unsigned short* __restrict__ xb) {
  int i = (blockIdx.x * 256 + threadIdx.x) * 4;
  float4 v = *(const float4*)(x + i);
  ushort4 o;
  o.x = f2bf(v.x); o.y = f2bf(v.y); o.z = f2bf(v.z); o.w = f2bf(v.w);
  *(ushort4*)(xb + i) = o;
}

// ---- fused transpose+cast of all 4 weights ----
__global__ void transpose_all_kernel(const float* __restrict__ Wq, const float* __restrict__ Wk,
                                     const float* __restrict__ Wv, const float* __restrict__ Wo,
                                     unsigned short* __restrict__ WqkvT,
                                     unsigned short* __restrict__ WoT) {
  __shared__ float s[32][33];
  int bx = blockIdx.x, k0 = blockIdx.y * 32;
  const float* W;
  unsigned short* dst;
  int N, n0, drow;
  if (bx < 64)       { W = Wq; dst = WqkvT; N = 2048; n0 = bx * 32;        drow = n0; }
  else if (bx < 80)  { W = Wk; dst = WqkvT; N = 512;  n0 = (bx - 64) * 32; drow = 2048 + n0; }
  else if (bx < 96)  { W = Wv; dst = WqkvT; N = 512;  n0 = (bx - 80) * 32; drow = 2560 + n0; }
  else               { W = Wo; dst = WoT;   N = 2048; n0 = (bx - 96) * 32; drow = n0; }
  int tx = threadIdx.x, ty = threadIdx.y;  // (32,8)
#pragma unroll
  for (int j = 0; j < 4; ++j)
    s[ty + j * 8][tx] = W[(size_t)(k0 + ty + j * 8) * N + n0 + tx];
  __syncthreads();
#pragma unroll
  for (int j = 0; j < 4; ++j)
    dst[(size_t)(drow + ty + j * 8) * 2048 + k0 + tx] = f2bf(s[tx][ty + j * 8]);
}

// ---------------- GEMM: TM x 128 tile, pipelined K-loop ----------------
template <int TM, bool OUT_F32>
__global__ __launch_bounds__(256, 2) void gemm_kernel(
    const unsigned short* __restrict__ A, const unsigned short* __restrict__ BT,
    const float* __restrict__ bq, const float* __restrict__ bk, const float* __restrict__ bv,
    void* __restrict__ Cout, int N) {
  const int K = 2048;
  const int MI = TM / 32;       // m-frags per wave
  __shared__ unsigned short sA[2][TM * 32];
  __shared__ unsigned short sB[2][128 * 32];
  const int m0 = blockIdx.y * TM, n0 = blockIdx.x * 128;
  const int tid = threadIdx.x;
  const int lane = tid & 63, w = tid >> 6;
  const int l15 = lane & 15, quad = lane >> 4;
  const int wm = (w & 1) * (TM / 2), wn = (w >> 1) * 64;

  f32x4 acc[MI][4];
#pragma unroll
  for (int i = 0; i < MI; ++i)
#pragma unroll
    for (int j = 0; j < 4; ++j) {
      f32x4 z = {0.f, 0.f, 0.f, 0.f};
      acc[i][j] = z;
    }

  const unsigned short* ga = A + (size_t)(m0 + (tid >> 2)) * K + (tid & 3) * 8;
  const unsigned short* gb = BT + (size_t)(n0 + (tid >> 2)) * K + (tid & 3) * 8;

  auto issue = [&](int tile, int buf) {
    int kb = tile * 32;
#pragma unroll
    for (int i = 0; i < TM / 64; ++i)
      gload_lds16(ga + (size_t)(i * 64) * K + kb, &sA[buf][i * 64 * 32 + tid * 8]);
    gload_lds16(gb + kb, &sB[buf][tid * 8]);
    gload_lds16(gb + (size_t)64 * K + kb, &sB[buf][64 * 32 + tid * 8]);
  };

  issue(0, 0);
  for (int t = 0; t < 64; ++t) {
    int tn = (t + 1 < 64) ? t + 1 : 63;  // clamped dummy prefetch on last iter
    issue(tn, (t + 1) & 1);
    if (TM == 128)
      asm volatile("s_waitcnt vmcnt(4)" ::: "memory");
    else
      asm volatile("s_waitcnt vmcnt(3)" ::: "memory");
    __builtin_amdgcn_s_barrier();
    const unsigned short* bA = sA[t & 1];
    const unsigned short* bB = sB[t & 1];
    bf16x8 af[MI], bfr[4];
#pragma unroll
    for (int i = 0; i < MI; ++i)
      af[i] = *(const bf16x8*)(bA + (wm + i * 16 + l15) * 32 + quad * 8);
#pragma unroll
    for (int i = 0; i < 4; ++i)
      bfr[i] = *(const bf16x8*)(bB + (wn + i * 16 + l15) * 32 + quad * 8);
#pragma unroll
    for (int mi = 0; mi < MI; ++mi)
#pragma unroll
      for (int ni = 0; ni < 4; ++ni)
        acc[mi][ni] = __builtin_amdgcn_mfma_f32_16x16x32_bf16(af[mi], bfr[ni], acc[mi][ni], 0, 0, 0);
    asm volatile("s_waitcnt lgkmcnt(0)" ::: "memory");
    __builtin_amdgcn_s_barrier();
  }

#pragma unroll
  for (int mi = 0; mi < MI; ++mi)
#pragma unroll
    for (int ni = 0; ni < 4; ++ni) {
      int col = n0 + wn + ni * 16 + l15;
      float bvv = 0.f;
      if (bq) bvv = (col < 2048) ? bq[col] : (col < 2560 ? bk[col - 2048] : bv[col - 2560]);
#pragma unroll
      for (int r = 0; r < 4; ++r) {
        int row = m0 + wm + mi * 16 + quad * 4 + r;
        float v = acc[mi][ni][r] + bvv;
        if (OUT_F32)
          ((float*)Cout)[(size_t)row * N + col] = v;
        else
          ((unsigned short*)Cout)[(size_t)row * N + col] = f2bf(v);
      }
    }
}

// ------- fused KV-cache build -------
__global__ void build_kv_kernel(const unsigned short* __restrict__ qkv,
                                const float* __restrict__ past_k,
                                const float* __restrict__ past_v,
                                const float* __restrict__ cosb, const float* __restrict__ sinb,
                                unsigned short* __restrict__ Kc,
                                unsigned short* __restrict__ Vc) {
  __shared__ unsigned short s[32][72];
  int tid = threadIdx.x;
  if (blockIdx.x < 4096) {
    int idx = blockIdx.x * 256 + tid;
    int d = idx & 31;
    int t = (idx >> 5) & 2047;
    int bh = idx >> 16;
    size_t obase = ((size_t)bh * 2048 + t) * 64 + d;
    if (t < 1024) {
      size_t pb = ((size_t)bh * 1024 + t) * 64 + d;
      Kc[obase] = f2bf(past_k[pb]);
      Kc[obase + 32] = f2bf(past_k[pb + 32]);
    } else {
      int l = t - 1024;
      int b = bh >> 3, hk = bh & 7;
      size_t qb = ((size_t)(b * 1024 + l)) * 3072 + 2048 + hk * 64 + d;
      float k0 = bf2f(qkv[qb]), k1 = bf2f(qkv[qb + 32]);
      float c = cosb[l * 64 + d], sn = sinb[l * 64 + d];
      Kc[obase] = f2bf(k0 * c - k1 * sn);
      Kc[obase + 32] = f2bf(k1 * c + k0 * sn);
    }
  } else {
    int bx = blockIdx.x - 4096;
    int t0 = (bx & 63) * 32;
    int bh = bx >> 6;
#pragma unroll
    for (int i = 0; i < 8; ++i) {
      int e = tid + 256 * i;
      int tl = e >> 6, d = e & 63;
      int t = t0 + tl;
      unsigned short val;
      if (t < 1024) {
        val = f2bf(past_v[((size_t)bh * 1024 + t) * 64 + d]);
      } else {
        int b = bh >> 3, hk = bh & 7;
        int l = t - 1024;
        val = qkv[(size_t)(b * 1024 + l) * 3072 + 2560 + hk * 64 + d];
      }
      s[tl][d] = val;
    }
    __syncthreads();
#pragma unroll
    for (int i = 0; i < 8; ++i) {
      int e = tid + 256 * i;
      int d = e >> 5, tl = e & 31;
      Vc[((size_t)bh * 64 + d) * 2048 + t0 + tl] = s[tl][d];
    }
  }
}

// ---------------- flash attention v6: GQA-shared KV tiles through LDS ----------------
// Block = (b, hk, 32-row q-chunk); 4 waves, wave w owns head hk*4+w. All waves
// consume the SAME K/V tile, staged once per block into padded LDS (stride 72
// shorts breaks the 128B-row bank aliasing), double-buffered with ONE
// __syncthreads per tile: issue global loads for kt+1 -> compute kt from LDS
// (full tile body hides load latency) -> write staged regs to other buffer ->
// barrier. L2 K/V traffic drops 4x vs direct-from-global (800->200 MB).
// Per-wave: exp2-lite softmax (scale*log2e folded into Q, no running max),
// additive l-sum, per-head output => no cross-wave combine, v2 epilogue.
#define LSTR 72
__global__ __launch_bounds__(256, 2) void attn_kernel(
    const unsigned short* __restrict__ qkv,  // [B*L][3072]
    const unsigned short* __restrict__ Kc,   // [B][NKV][T][D]
    const unsigned short* __restrict__ Vc,   // [B][NKV][D][T]
    const float* __restrict__ cosb, const float* __restrict__ sinb,
    unsigned short* __restrict__ O) {        // [B*L][2048]
  __shared__ unsigned short sK[2][64 * LSTR];   // [t-local][d]
  __shared__ unsigned short sV[2][64 * LSTR];   // [d][t-local]
  __shared__ unsigned short sPs[4][32 * LSTR];  // per-wave P round-trip

  int flat = blockIdx.x;                      // 0..511
  int pair = (flat & 7) * 2 + ((flat >> 3) & 1);  // b*8+hk, XCD-pinned
  int b = pair >> 3, hk = pair & 7;
  int qt = flat >> 4;                         // 0..31
  int q0 = qt * 32;

  const int tid = threadIdx.x;
  const int lane = tid & 63, w = tid >> 6;
  const int l15 = lane & 15, quad = lane >> 4;
  const int h = hk * 4 + w;                   // wave-private head

  unsigned short* sP = sPs[w];

  union U8 { bf16x8 v; unsigned short u[8]; };

  // ---- Q fragments: inline RoPE + fold in scale*log2(e) ----
  const float SC = 0.125f * 1.44269504f;
  bf16x8 qf[2][2];
#pragma unroll
  for (int mi = 0; mi < 2; ++mi) {
    int row = q0 + mi * 16 + l15;
    const unsigned short* qrow = qkv + (size_t)(b * 1024 + row) * 3072 + h * 64;
    int d0 = quad * 8;
    U8 lo, hig, f0, f1;
    lo.v = *(const bf16x8*)(qrow + d0);
    hig.v = *(const bf16x8*)(qrow + 32 + d0);
    float4 ca = *(const float4*)(cosb + row * 64 + d0);
    float4 cb = *(const float4*)(cosb + row * 64 + d0 + 4);
    float4 sa = *(const float4*)(sinb + row * 64 + d0);
    float4 sb = *(const float4*)(sinb + row * 64 + d0 + 4);
    float c[8] = {ca.x, ca.y, ca.z, ca.w, cb.x, cb.y, cb.z, cb.w};
    float sn[8] = {sa.x, sa.y, sa.z, sa.w, sb.x, sb.y, sb.z, sb.w};
#pragma unroll
    for (int j = 0; j < 8; ++j) {
      float ql = bf2f(lo.u[j]), qh = bf2f(hig.u[j]);
      float cc = c[j] * SC, ss = sn[j] * SC;
      f0.u[j] = f2bf(ql * cc - qh * ss);
      f1.u[j] = f2bf(qh * cc + ql * ss);
    }
    qf[mi][0] = f0.v;
    qf[mi][1] = f1.v;
  }

  const unsigned short* Kb = Kc + ((size_t)b * 8 + hk) * (2048 * 64);
  const unsigned short* Vb = Vc + ((size_t)b * 8 + hk) * (64 * 2048);

  // staging map: thread -> (row sr, cols sc..sc+7), two passes of 32 rows
  const int sr = tid >> 3;        // 0..31
  const int sc = (tid & 7) * 8;   // 0,8,..,56

  uint4 kreg0, kreg1, vreg0, vreg1;
  auto issueLoads = [&](int t0) {
    kreg0 = *(const uint4*)(Kb + (size_t)(t0 + sr) * 64 + sc);
    kreg1 = *(const uint4*)(Kb + (size_t)(t0 + sr + 32) * 64 + sc);
    vreg0 = *(const uint4*)(Vb + (size_t)sr * 2048 + t0 + sc);
    vreg1 = *(const uint4*)(Vb + (size_t)(sr + 32) * 2048 + t0 + sc);
  };
  auto writeStage = [&](int buf) {
    *(uint4*)(&sK[buf][sr * LSTR + sc]) = kreg0;
    *(uint4*)(&sK[buf][(sr + 32) * LSTR + sc]) = kreg1;
    *(uint4*)(&sV[buf][sr * LSTR + sc]) = vreg0;
    *(uint4*)(&sV[buf][(sr + 32) * LSTR + sc]) = vreg1;
  };

  f32x4 oacc[2][4];
  float lsum[2][4];
#pragma unroll
  for (int mi = 0; mi < 2; ++mi) {
#pragma unroll
    for (int nd = 0; nd < 4; ++nd) {
      f32x4 z = {0.f, 0.f, 0.f, 0.f};
      oacc[mi][nd] = z;
    }
#pragma unroll
    for (int r = 0; r < 4; ++r) lsum[mi][r] = 0.f;
  }

  const int ntile = (q0 + 32 + 1024 + 63) >> 6;  // 17..32, identical for all 4 waves

  issueLoads(0);
  writeStage(0);
  __syncthreads();

  for (int kt = 0; kt < ntile; ++kt) {
    int t0n = (kt + 1) * 64;
    if (t0n > 1984) t0n = 1984;   // clamped dummy prefetch on last iter
    issueLoads(t0n);

    const int t0 = kt * 64;
    const int buf = kt & 1;
    const unsigned short* bK = sK[buf];
    const unsigned short* bV = sV[buf];

    // S = (Q*SC') K^T  -- K frags from LDS
    f32x4 sacc[2][4];
#pragma unroll
    for (int mi = 0; mi < 2; ++mi)
#pragma unroll
      for (int nt = 0; nt < 4; ++nt) {
        f32x4 z = {0.f, 0.f, 0.f, 0.f};
        sacc[mi][nt] = z;
      }
#pragma unroll
    for (int ks = 0; ks < 2; ++ks)
#pragma unroll
      for (int nt = 0; nt < 4; ++nt) {
        bf16x8 kf = *(const bf16x8*)(bK + (nt * 16 + l15) * LSTR + ks * 32 + quad * 8);
#pragma unroll
        for (int mi = 0; mi < 2; ++mi)
          sacc[mi][nt] = __builtin_amdgcn_mfma_f32_16x16x32_bf16(qf[mi][ks], kf, sacc[mi][nt], 0, 0, 0);
      }

    // softmax-lite + P -> per-wave sP
    const bool diag = (t0 + 63 > q0 + Pc);
    if (!diag) {
#pragma unroll
      for (int mi = 0; mi < 2; ++mi)
#pragma unroll
        for (int nt = 0; nt < 4; ++nt)
#pragma unroll
          for (int r = 0; r < 4; ++r) {
            float pv = exp2_fast(sacc[mi][nt][r]);
            lsum[mi][r] += pv;
            sP[(mi * 16 + quad * 4 + r) * LSTR + nt * 16 + l15] = f2bf_rhu(pv);
          }
    } else {
#pragma unroll
      for (int mi = 0; mi < 2; ++mi)
#pragma unroll
        for (int nt = 0; nt < 4; ++nt)
#pragma unroll
          for (int r = 0; r < 4; ++r) {
            int tg = t0 + nt * 16 + l15;
            int rg = q0 + mi * 16 + quad * 4 + r;
            float pv = (tg > rg + Pc) ? 0.f : exp2_fast(sacc[mi][nt][r]);
            lsum[mi][r] += pv;
            sP[(mi * 16 + quad * 4 + r) * LSTR + nt * 16 + l15] = f2bf_rhu(pv);
          }
    }
    asm volatile("s_waitcnt lgkmcnt(0)" ::: "memory");

    // O += P @ V  -- V frags from LDS (read once, used by both m-frags)
    bf16x8 vf[2][4];
#pragma unroll
    for (int tk = 0; tk < 2; ++tk)
#pragma unroll
      for (int nd = 0; nd < 4; ++nd)
        vf[tk][nd] = *(const bf16x8*)(bV + (nd * 16 + l15) * LSTR + tk * 32 + quad * 8);
#pragma unroll
    for (int mi = 0; mi < 2; ++mi)
#pragma unroll
      for (int tk = 0; tk < 2; ++tk) {
        bf16x8 a = *(const bf16x8*)(sP + (mi * 16 + l15) * LSTR + tk * 32 + quad * 8);
#pragma unroll
        for (int nd = 0; nd < 4; ++nd)
          oacc[mi][nd] = __builtin_amdgcn_mfma_f32_16x16x32_bf16(a, vf[tk][nd], oacc[mi][nd], 0, 0, 0);
      }

    // stage tile kt+1 into the other buffer; one barrier per tile
    writeStage(buf ^ 1);
    __syncthreads();
  }

  // epilogue: per-wave (each wave owns its head) -- reduce lsum across l15 lanes
  float inv[2][4];
#pragma unroll
  for (int mi = 0; mi < 2; ++mi)
#pragma unroll
    for (int r = 0; r < 4; ++r) {
      float v = lsum[mi][r];
      v += __shfl_xor(v, 1);
      v += __shfl_xor(v, 2);
      v += __shfl_xor(v, 4);
      v += __shfl_xor(v, 8);
      inv[mi][r] = 1.f / v;
    }
#pragma unroll
  for (int mi = 0; mi < 2; ++mi)
#pragma unroll
    for (int nd = 0; nd < 4; ++nd) {
      int col = h * 64 + nd * 16 + l15;
#pragma unroll
      for (int r = 0; r < 4; ++r) {
        int row = b * 1024 + q0 + mi * 16 + quad * 4 + r;
        O[(size_t)row * 2048 + col] = f2bf(oacc[mi][nd][r] * inv[mi][r]);
      }
    }
}

extern "C" void kernel_launch(void* const* d_in, const int* in_sizes, int n_in,
                              void* d_out, int out_size, void* d_ws, size_t ws_size,
                              hipStream_t stream) {
  const float* x      = (const float*)d_in[0];
  const float* cosb   = (const float*)d_in[2];
  const float* sinb   = (const float*)d_in[3];
  const float* past_k = (const float*)d_in[4];
  const float* past_v = (const float*)d_in[5];
  const float* Wq     = (const float*)d_in[6];
  const float* bq     = (const float*)d_in[7];
  const float* Wk     = (const float*)d_in[8];
  const float* bk     = (const float*)d_in[9];
  const float* Wv     = (const float*)d_in[10];
  const float* bv     = (const float*)d_in[11];
  const float* Wo     = (const float*)d_in[12];
  float* out = (float*)d_out;

  char* ws = (char*)d_ws;
  unsigned short* xb    = (unsigned short*)(ws + ((size_t)0 << 20));   // 8 MB
  unsigned short* WqkvT = (unsigned short*)(ws + ((size_t)8 << 20));   // 12 MB
  unsigned short* WoT   = (unsigned short*)(ws + ((size_t)20 << 20));  // 8 MB
  unsigned short* qkvb  = (unsigned short*)(ws + ((size_t)28 << 20));  // 12 MB
  unsigned short* Kc    = (unsigned short*)(ws + ((size_t)40 << 20));  // 4 MB
  unsigned short* Vc    = (unsigned short*)(ws + ((size_t)44 << 20));  // 4 MB
  unsigned short* attno = (unsigned short*)(ws + ((size_t)48 << 20));  // 8 MB

  cast_x_kernel<<<4096, 256, 0, stream>>>(x, xb);
  transpose_all_kernel<<<dim3(160, 64), dim3(32, 8), 0, stream>>>(Wq, Wk, Wv, Wo, WqkvT, WoT);

  gemm_kernel<64, false><<<dim3(24, 32), 256, 0, stream>>>(xb, WqkvT, bq, bk, bv, qkvb, 3072);

  build_kv_kernel<<<5120, 256, 0, stream>>>(qkvb, past_k, past_v, cosb, sinb, Kc, Vc);

  attn_kernel<<<512, 256, 0, stream>>>(qkvb, Kc, Vc, cosb, sinb, attno);

  gemm_kernel<64, true><<<dim3(16, 32), 256, 0, stream>>>(attno, WoT, nullptr, nullptr, nullptr, out, 2048);
}